// Round 1
// baseline (429.358 us; speedup 1.0000x reference)
//
#include <hip/hip_runtime.h>
#include <stdint.h>

// GraphConvLayer: out[n,:] = W[type[n]] @ (A @ x)[n,:]
// N=16384, D=128, T=8.  A is 1 GiB f32, read exactly once -> HBM-bound floor ~163us.

#define N_NODES 16384
#define DIM     128
#define NTYPES  8
#define BM      64
#define BK      64
#define NIT     (N_NODES / BK)   // 256

typedef float f32x4 __attribute__((ext_vector_type(4)));
typedef short s16x8 __attribute__((ext_vector_type(8)));

// bf16 staging buffers (module-static device memory; rewritten every call)
__device__ __attribute__((aligned(16))) unsigned short g_xT[DIM * N_NODES];      // [d][n], 4 MiB
__device__ __attribute__((aligned(16))) unsigned short g_Wb[NTYPES * DIM * DIM]; // [t][o][d], 256 KiB

__device__ __forceinline__ unsigned short f2b(float f) {
    unsigned int u = __float_as_uint(f);
    u += 0x7FFFu + ((u >> 16) & 1u);   // round-to-nearest-even
    return (unsigned short)(u >> 16);
}
#define BF_LO(u) __uint_as_float((unsigned int)(u) << 16)
#define BF_HI(u) __uint_as_float((unsigned int)(u) & 0xFFFF0000u)

// ---------------- prep kernels ----------------

__global__ void prep_xT(const float* __restrict__ x) {
    int n = blockIdx.x * 256 + threadIdx.x;          // 64 blocks x 256
    const float* row = x + (size_t)n * DIM;
#pragma unroll
    for (int d0 = 0; d0 < DIM; d0 += 4) {
        float4 v = *(const float4*)(row + d0);
        g_xT[(d0 + 0) * N_NODES + n] = f2b(v.x);
        g_xT[(d0 + 1) * N_NODES + n] = f2b(v.y);
        g_xT[(d0 + 2) * N_NODES + n] = f2b(v.z);
        g_xT[(d0 + 3) * N_NODES + n] = f2b(v.w);
    }
}

__global__ void prep_W(const float* __restrict__ w) {
    int i = (blockIdx.x * 256 + threadIdx.x) * 4;    // 128 blocks x 256
    float4 v = *(const float4*)(w + i);
    ushort4 o;
    o.x = f2b(v.x); o.y = f2b(v.y); o.z = f2b(v.z); o.w = f2b(v.w);
    *(ushort4*)(g_Wb + i) = o;
}

// ---------------- main fused kernel ----------------

#define LDS_STRIDE 72                       // 64 + 8 pad shorts = 144 B = 9 x 16B granules
#define ABYTES (BM * LDS_STRIDE * 2)        // 9216
#define XBYTES (DIM * LDS_STRIDE * 2)       // 18432
#define BUFBYTES (ABYTES + XBYTES)          // 27648

__global__ __launch_bounds__(512, 2) void gconv_main(
    const float* __restrict__ adj,
    const int* __restrict__ types,
    float* __restrict__ out)
{
    __shared__ __align__(16) unsigned char lds[2 * BUFBYTES]; // 55296 B (also reused as agg[64][132] f32)

    const int tid  = threadIdx.x;
    const int w    = tid >> 6;
    const int lane = tid & 63;
    const int m0   = blockIdx.x * BM;

    // wave tiling: rows (w&3)*16..+16, cols (w>>2)*64..+64  (4 n-tiles of 16)
    const int mrow = (w & 3) * 16;
    const int ncol = (w >> 2) * 64;

    f32x4 acc[4] = {};

    // staging index math
    const int ar0 = tid >> 4;                 // A row for j=0 (0..31); j=1 adds 32
    const int ak  = (tid & 15) * 4;           // A k offset (float4)
    const int xc0 = tid >> 3;                 // xT col for j=0 (0..63); j=1 adds 64
    const int xg  = tid & 7;                  // 16B granule within col

    const float* aBase = adj + (size_t)m0 * N_NODES;

    float4 aReg[2];
    uint4  xReg[2];

    auto LOADG = [&](int t) {
        const int kb = t * BK;
        aReg[0] = *(const float4*)(aBase + (size_t)ar0 * N_NODES + kb + ak);
        aReg[1] = *(const float4*)(aBase + (size_t)(ar0 + 32) * N_NODES + kb + ak);
        xReg[0] = *(const uint4*)(g_xT + (size_t)xc0 * N_NODES + kb + xg * 8);
        xReg[1] = *(const uint4*)(g_xT + (size_t)(xc0 + 64) * N_NODES + kb + xg * 8);
    };
    auto STORE = [&](int buf) {
        unsigned short* As = (unsigned short*)(lds + buf * BUFBYTES);
        unsigned short* Xs = As + BM * LDS_STRIDE;
        uint2 p;
        p.x = (unsigned int)f2b(aReg[0].x) | ((unsigned int)f2b(aReg[0].y) << 16);
        p.y = (unsigned int)f2b(aReg[0].z) | ((unsigned int)f2b(aReg[0].w) << 16);
        *(uint2*)(As + ar0 * LDS_STRIDE + ak) = p;
        p.x = (unsigned int)f2b(aReg[1].x) | ((unsigned int)f2b(aReg[1].y) << 16);
        p.y = (unsigned int)f2b(aReg[1].z) | ((unsigned int)f2b(aReg[1].w) << 16);
        *(uint2*)(As + (ar0 + 32) * LDS_STRIDE + ak) = p;
        *(uint4*)(Xs + xc0 * LDS_STRIDE + xg * 8) = xReg[0];
        *(uint4*)(Xs + (xc0 + 64) * LDS_STRIDE + xg * 8) = xReg[1];
    };
    auto COMPUTE = [&](int buf) {
        const unsigned short* As = (const unsigned short*)(lds + buf * BUFBYTES);
        const unsigned short* Xs = As + BM * LDS_STRIDE;
#pragma unroll
        for (int kc = 0; kc < 2; ++kc) {
            const int kk = kc * 32 + (lane >> 4) * 8;
            s16x8 a = *(const s16x8*)(As + (mrow + (lane & 15)) * LDS_STRIDE + kk);
#pragma unroll
            for (int nt = 0; nt < 4; ++nt) {
                s16x8 b = *(const s16x8*)(Xs + (ncol + nt * 16 + (lane & 15)) * LDS_STRIDE + kk);
                asm("v_mfma_f32_16x16x32_bf16 %0, %1, %2, %0" : "+v"(acc[nt]) : "v"(a), "v"(b));
            }
        }
    };

    // K loop: double-buffered, one barrier per iteration; next-tile loads
    // issue before compute of current tile (HBM latency hides under MFMA).
    LOADG(0);
    STORE(0);
    int cur = 0;
    for (int t = 0; t < NIT; ++t) {
        __syncthreads();
        if (t + 1 < NIT) LOADG(t + 1);
        COMPUTE(cur);
        if (t + 1 < NIT) STORE(cur ^ 1);
        cur ^= 1;
    }
    __syncthreads();

    // ---- epilogue: acc -> LDS agg (f32, padded), then per-row W[type] dots ----
    float* agg = (float*)lds;   // [64][132] = 33792 B
#pragma unroll
    for (int nt = 0; nt < 4; ++nt)
#pragma unroll
        for (int r = 0; r < 4; ++r)
            agg[(mrow + (lane >> 4) * 4 + r) * 132 + ncol + nt * 16 + (lane & 15)] = acc[nt][r];
    __syncthreads();

    const int rbase = w * 8;   // 8 rows per wave
    for (int rr = 0; rr < 8; ++rr) {
        const int rw = rbase + rr;
        const int nn = m0 + rw;
        const int ty = types[nn];                      // wave-uniform
        const unsigned short* Wt = g_Wb + ty * (DIM * DIM);
        const int o0 = lane * 2;
        const float* aggRow = agg + rw * 132;
        float s0 = 0.f, s1 = 0.f;
#pragma unroll
        for (int d0 = 0; d0 < DIM; d0 += 8) {
            float4 ga = *(const float4*)(aggRow + d0);
            float4 gb = *(const float4*)(aggRow + d0 + 4);
            uint4 wa = *(const uint4*)(Wt + o0 * DIM + d0);
            uint4 wb = *(const uint4*)(Wt + (o0 + 1) * DIM + d0);
            s0 += ga.x * BF_LO(wa.x) + ga.y * BF_HI(wa.x) + ga.z * BF_LO(wa.y) + ga.w * BF_HI(wa.y);
            s0 += gb.x * BF_LO(wa.z) + gb.y * BF_HI(wa.z) + gb.z * BF_LO(wa.w) + gb.w * BF_HI(wa.w);
            s1 += ga.x * BF_LO(wb.x) + ga.y * BF_HI(wb.x) + ga.z * BF_LO(wb.y) + ga.w * BF_HI(wb.y);
            s1 += gb.x * BF_LO(wb.z) + gb.y * BF_HI(wb.z) + gb.z * BF_LO(wb.w) + gb.w * BF_HI(wb.w);
        }
        float2 res; res.x = s0; res.y = s1;
        *(float2*)(out + (size_t)nn * DIM + o0) = res;
    }
}

// ---------------- launch ----------------

extern "C" void kernel_launch(void* const* d_in, const int* in_sizes, int n_in,
                              void* d_out, int out_size, void* d_ws, size_t ws_size,
                              hipStream_t stream) {
    const float* x     = (const float*)d_in[0];
    const int*   types = (const int*)d_in[1];
    const float* adj   = (const float*)d_in[2];
    const float* wt    = (const float*)d_in[3];
    float* out = (float*)d_out;

    hipLaunchKernelGGL(prep_xT, dim3(N_NODES / 256), dim3(256), 0, stream, x);
    hipLaunchKernelGGL(prep_W,  dim3((NTYPES * DIM * DIM) / (256 * 4)), dim3(256), 0, stream, wt);
    hipLaunchKernelGGL(gconv_main, dim3(N_NODES / BM), dim3(512), 0, stream, adj, types, out);
}